// Round 15
// baseline (210.618 us; speedup 1.0000x reference)
//
#include <hip/hip_runtime.h>
#include <cfloat>

#define BB 4
#define LL 2048
#define DSTATE 16
#define CH 32
#define NC 64

typedef unsigned short u16;
typedef __attribute__((ext_vector_type(8))) short bf16x8;
typedef __attribute__((ext_vector_type(4))) float f32x4;

__device__ inline u16 f2b(float v) {
  union { float f; unsigned u; } c; c.f = v;
  unsigned r = c.u + 0x7fffu + ((c.u >> 16) & 1u);
  return (u16)(r >> 16);
}
__device__ inline float b2f(u16 h) {
  union { unsigned u; float f; } c; c.u = ((unsigned)h) << 16;
  return c.f;
}
__device__ inline void atomicMaxF(float* a, float v) {
  if (v >= 0.f) atomicMax((int*)a, __float_as_int(v));
  else atomicMin((unsigned int*)a, __float_as_uint(v));
}

#define GLOAD16(gsrc, ldst) \
  __builtin_amdgcn_global_load_lds( \
      (const __attribute__((address_space(1))) unsigned int*)(gsrc), \
      (__attribute__((address_space(3))) unsigned int*)(ldst), 16, 0, 0)

// ------- conv1 fused with im2col: x (B,L,9) -> A' (8192,768)=[Htaps|Ltaps] -------
__global__ __launch_bounds__(256) void k1_conv1A(const float* __restrict__ x,
    const float* __restrict__ w, const float* __restrict__ bias,
    u16* __restrict__ A) {
  int idx = blockIdx.x * 256 + threadIdx.x;  // (b,t,i)
  int i = idx & 127;
  int t = (idx >> 7) & (LL - 1);
  int b = idx >> 18;
  float acc = bias[i];
#pragma unroll
  for (int k = 0; k < 3; ++k) {
    int ts = t + k - 1;
    if (ts < 0 || ts >= LL) continue;
    const float* xr = x + (b * LL + ts) * 9;
    const float* wr = w + i * 27 + k;
#pragma unroll
    for (int c = 0; c < 9; ++c) acc += xr[c] * wr[c * 3];
  }
  float v = fmaxf(acc, 0.f);
  u16 h = f2b(v), l = f2b(v - b2f(h));
#pragma unroll
  for (int tap = 0; tap < 3; ++tap) {
    int rr = t + 1 - tap;
    if (rr < 0 || rr >= LL) continue;
    u16* rp = A + ((size_t)(b * LL + rr)) * 768 + tap * 128 + i;
    rp[0] = h; rp[384] = l;
  }
  if (t == 0) {
    u16* rp = A + ((size_t)(b * LL)) * 768 + i;
    rp[0] = 0; rp[384] = 0;
  }
  if (t == LL - 1) {
    u16* rp = A + ((size_t)(b * LL + LL - 1)) * 768 + 256 + i;
    rp[0] = 0; rp[384] = 0;
  }
}

// ------- ALL weight prep (bf16-H only) + combined dt/BC weight + pooled init ----
__global__ __launch_bounds__(256) void k_prep(const float* __restrict__ wc2,
    const float* __restrict__ wip, const float* __restrict__ wop,
    const float* __restrict__ xw, const float* __restrict__ dtw,
    u16* __restrict__ dc2, u16* __restrict__ dip, u16* __restrict__ dop,
    u16* __restrict__ dcb, float* __restrict__ pooled) {
  int idx = blockIdx.x * 256 + threadIdx.x;
  if (idx < 98304) {                        // conv2: (256,128,3) -> WH[o][tap*128+i]
    int o = idx / 384, r2 = idx - o * 384;
    int tap = r2 >> 7, i = r2 & 127;
    dc2[(size_t)o * 384 + r2] = f2b(wc2[o * 384 + i * 3 + tap]);
  } else if (idx < 360448) {                // in_proj (1024,256) -> WH
    int j = idx - 98304;
    dip[j] = f2b(wip[j]);
  } else if (idx < 491520) {                // out_proj (256,512) -> WH
    int j = idx - 360448;
    dop[j] = f2b(wop[j]);
  } else if (idx < 492544) {
    pooled[idx - 491520] = -FLT_MAX;
  } else if (idx < 787456) {                // comb: rows<512 dtw@xw16; 512..543 B/C; else 0
    int j = idx - 492544;                   // n*512 + k, n<576
    int n = j >> 9, k = j & 511;
    float v = 0.f;
    if (n < 512) {
      const float* dr = dtw + n * 16;
#pragma unroll
      for (int q = 0; q < 16; ++q) v += dr[q] * xw[q * 512 + k];
    } else if (n < 544) {
      v = xw[(16 + n - 512) * 512 + k];
    }
    dcb[(size_t)n * 512 + k] = f2b(v);
  }
}

// ======= MFMA GEMM, triple-buffered with COUNTED vmcnt (T3/T4-minimal) =======
// C = A[M,K] @ B'[N,K]^T; A=[H|L] split, B=bf16 weights logical [WH|WH] (wraps at KB).
// Per K-step: raw s_barrier + s_waitcnt vmcnt(S) (never 0 mid-loop) -- loads for
// tile t+1 stay in flight across the barrier; stage t+2 issued after barrier.
// EPI 0: fp32 C. EPI 1: bias+relu -> [H|L]. EPI 2: max-pool atomic. EPI 3: dt+BC.
template <int TM, int TN, int EPI, int NBX>
__global__ __launch_bounds__(256) void k_mm(
    const u16* __restrict__ A, const u16* __restrict__ B,
    float* __restrict__ C, const float* __restrict__ bias,
    u16* __restrict__ osp, float* __restrict__ xdb, int N, int K, int KB) {
  constexpr int WM = TM / 2, WN = TN / 2;
  constexpr int NA = WM / 16, NB = WN / 16;
  constexpr int S = TM / 32 + TN / 32;      // GLOAD16s per thread per stage
  __shared__ u16 As[3][TM * 64];
  __shared__ u16 Bs[3][TN * 64];
  __shared__ float cmw[2][TN];
  const int tid = threadIdx.x;
  const int lane = tid & 63;
  const int wid = tid >> 6;
  const int wr = wid >> 1, wc = wid & 1;
  int bid = blockIdx.y * NBX + blockIdx.x;
  int nwg = gridDim.y * NBX;
  int swz = (bid & 7) * (nwg >> 3) + (bid >> 3);
  int bm = swz / NBX;
  int bn = swz - bm * NBX;
  const int m0 = bm * TM, n0 = bn * TN;
  const int lrow = lane & 15, lg = lane >> 4;
  const int srow = tid >> 3, sg = tid & 7;
  const int NT = K >> 6;

  f32x4 acc[NA][NB] = {};

  auto stage = [&](int buf, int k0) {
#pragma unroll
    for (int r = 0; r < TM / 32; ++r) {
      int row = r * 32 + srow;
      const u16* src = A + (size_t)(m0 + row) * K + k0 + ((sg ^ (row & 7)) << 3);
      GLOAD16(src, &As[buf][row * 64 + (sg << 3)]);
    }
    int kb = (k0 < KB) ? k0 : k0 - KB;      // B wraps: logical [WH|WH]
#pragma unroll
    for (int r = 0; r < TN / 32; ++r) {
      int row = r * 32 + srow;
      const u16* src = B + (size_t)(n0 + row) * KB + kb + ((sg ^ (row & 7)) << 3);
      GLOAD16(src, &Bs[buf][row * 64 + (sg << 3)]);
    }
  };

  stage(0, 0);
  if (NT > 1) stage(1, 64);
  int cur = 0, st = 2;
  for (int t = 0; t < NT; ++t) {
    // wait for tile t's loads only; tile t+1's stay in flight (counted vmcnt)
    if (t + 1 < NT) {
      if constexpr (S == 3) asm volatile("s_waitcnt vmcnt(3)" ::: "memory");
      else asm volatile("s_waitcnt vmcnt(4)" ::: "memory");
    } else {
      asm volatile("s_waitcnt vmcnt(0)" ::: "memory");
    }
    __builtin_amdgcn_s_barrier();
    if (t + 2 < NT) stage(st, (t + 2) << 6);
#pragma unroll
    for (int kc = 0; kc < 2; ++kc) {
      bf16x8 af[NA], bfr[NB];
#pragma unroll
      for (int i = 0; i < NA; ++i) {
        int row = wr * WM + i * 16 + lrow;
        int g = (kc * 4 + lg) ^ (row & 7);
        af[i] = *(const bf16x8*)&As[cur][row * 64 + (g << 3)];
      }
#pragma unroll
      for (int j = 0; j < NB; ++j) {
        int row = wc * WN + j * 16 + lrow;
        int g = (kc * 4 + lg) ^ (row & 7);
        bfr[j] = *(const bf16x8*)&Bs[cur][row * 64 + (g << 3)];
      }
#pragma unroll
      for (int i = 0; i < NA; ++i)
#pragma unroll
        for (int j = 0; j < NB; ++j)
          acc[i][j] = __builtin_amdgcn_mfma_f32_16x16x32_bf16(af[i], bfr[j], acc[i][j], 0, 0, 0);
    }
    cur = (cur == 2) ? 0 : cur + 1;
    st  = (st == 2) ? 0 : st + 1;
  }
  if constexpr (EPI == 2) {
    float mj[NB];
#pragma unroll
    for (int j = 0; j < NB; ++j) {
      float m = -FLT_MAX;
#pragma unroll
      for (int i = 0; i < NA; ++i)
#pragma unroll
        for (int r = 0; r < 4; ++r) m = fmaxf(m, acc[i][j][r]);
      m = fmaxf(m, __shfl_xor(m, 16, 64));
      m = fmaxf(m, __shfl_xor(m, 32, 64));
      mj[j] = m;
    }
    __syncthreads();
    if (lane < 16) {
#pragma unroll
      for (int j = 0; j < NB; ++j)
        cmw[wr][wc * WN + j * 16 + lane] = mj[j];
    }
    __syncthreads();
    if (tid < TN) {
      float v = fmaxf(cmw[0][tid], cmw[1][tid]);
      atomicMaxF(&C[(m0 >> 11) * 256 + n0 + tid], v);
    }
  } else {
#pragma unroll
    for (int i = 0; i < NA; ++i)
#pragma unroll
      for (int j = 0; j < NB; ++j)
#pragma unroll
        for (int r = 0; r < 4; ++r) {
          int row = m0 + wr * WM + i * 16 + lg * 4 + r;
          int col = n0 + wc * WN + j * 16 + lrow;
          if constexpr (EPI == 0) {
            C[(size_t)row * N + col] = acc[i][j][r];
          } else if constexpr (EPI == 1) {
            float v = fmaxf(acc[i][j][r] + bias[col], 0.f);
            u16 h = f2b(v), l = f2b(v - b2f(h));
            u16* rp = osp + (size_t)row * 512;
            rp[col] = h;
            rp[256 + col] = l;
          } else {  // EPI == 3: dt softplus + BC scatter
            float v = acc[i][j][r];
            if (col < 512) {
              float a = v + bias[col];
              C[(size_t)row * 512 + col] = (a > 20.f) ? a : __logf(1.f + __expf(a));
            } else if (col < 544) {
              xdb[(size_t)row * 48 + 16 + (col - 512)] = v;
            }
          }
        }
  }
}

// ------- depthwise causal conv4 + silu: xz -> uS (8192,1024)=[H|L] -------
__global__ __launch_bounds__(256) void k4_dwconv(const float* __restrict__ xz,
    const float* __restrict__ w, const float* __restrict__ bias,
    u16* __restrict__ uS) {
  int idx = blockIdx.x * 256 + threadIdx.x;
  int d = idx & 511;
  int t = (idx >> 9) & (LL - 1);
  int b = idx >> 20;
  float acc = bias[d];
#pragma unroll
  for (int k = 0; k < 4; ++k) {
    int tt = t - 3 + k;
    if (tt >= 0) acc += xz[(b * LL + tt) * 1024 + d] * w[d * 4 + k];
  }
  float v = acc / (1.f + __expf(-acc));
  u16 h = f2b(v), l = f2b(v - b2f(h));
  u16* rp = uS + (size_t)(b * LL + t) * 1024 + d;
  rp[0] = h;
  rp[512] = l;
}

// ======== chunked selective scan: 3 passes (u = H+L from uS) ========
__global__ __launch_bounds__(512) void k7a_pass1(const float* __restrict__ dt,
    const u16* __restrict__ uS, const float* __restrict__ xdbl,
    const float* __restrict__ A_log, float* __restrict__ hloc,
    float* __restrict__ dtsum) {
  __shared__ float Bs[CH][16];
  int b = blockIdx.x >> 6;
  int c = blockIdx.x & (NC - 1);
  int d = threadIdx.x;
  {
    int t = threadIdx.x >> 4, s = threadIdx.x & 15;
    Bs[t][s] = xdbl[(b * LL + c * CH + t) * 48 + 16 + s];
  }
  __syncthreads();
  float A_r[16];
#pragma unroll
  for (int s = 0; s < 16; ++s) A_r[s] = -__expf(A_log[d * 16 + s]);
  float h[16];
#pragma unroll
  for (int s = 0; s < 16; ++s) h[s] = 0.f;
  float dsum = 0.f;
  const float* dtp = dt + (size_t)(b * LL + c * CH) * 512 + d;
  const u16* up = uS + (size_t)(b * LL + c * CH) * 1024 + d;
  for (int t = 0; t < CH; ++t) {
    float dtv = dtp[t * 512];
    float uv = b2f(up[t * 1024]) + b2f(up[t * 1024 + 512]);
    float xv = dtv * uv;
    dsum += dtv;
#pragma unroll
    for (int s = 0; s < 16; ++s)
      h[s] = h[s] * __expf(dtv * A_r[s]) + xv * Bs[t][s];
  }
  int base = b * NC + c;
#pragma unroll
  for (int s = 0; s < 16; ++s) hloc[(base * 16 + s) * 512 + d] = h[s];
  dtsum[base * 512 + d] = dsum;
}

__global__ __launch_bounds__(512) void k7b_combine(const float* __restrict__ hloc,
    const float* __restrict__ dtsum, const float* __restrict__ A_log,
    float* __restrict__ h_in) {
  int g = blockIdx.x * 512 + threadIdx.x;
  int d = g & 511;
  int s = (g >> 9) & 15;
  int b = g >> 13;
  float A_r = -__expf(A_log[d * 16 + s]);
  float H = 0.f;
  for (int c = 0; c < NC; ++c) {
    int base = b * NC + c;
    h_in[(base * 16 + s) * 512 + d] = H;
    float P = __expf(A_r * dtsum[base * 512 + d]);
    H = P * H + hloc[(base * 16 + s) * 512 + d];
  }
}

// pass3: replay + gate; writes y2s (8192,1024) = [H | L]
__global__ __launch_bounds__(512) void k7c_pass3(const float* __restrict__ dt,
    const u16* __restrict__ uS, const float* __restrict__ xdbl,
    const float* __restrict__ xz, const float* __restrict__ A_log,
    const float* __restrict__ D_param, const float* __restrict__ h_in,
    u16* __restrict__ y2s) {
  __shared__ float BC[CH][32];
  int b = blockIdx.x >> 6;
  int c = blockIdx.x & (NC - 1);
  int d = threadIdx.x;
  for (int i = threadIdx.x; i < CH * 32; i += 512) {
    int t = i >> 5, j = i & 31;
    BC[t][j] = xdbl[(b * LL + c * CH + t) * 48 + 16 + j];
  }
  __syncthreads();
  float A_r[16];
#pragma unroll
  for (int s = 0; s < 16; ++s) A_r[s] = -__expf(A_log[d * 16 + s]);
  float Dv = D_param[d];
  int base = b * NC + c;
  float h[16];
#pragma unroll
  for (int s = 0; s < 16; ++s) h[s] = h_in[(base * 16 + s) * 512 + d];
  for (int t = 0; t < CH; ++t) {
    int row = b * LL + c * CH + t;
    float dtv = dt[(size_t)row * 512 + d];
    const u16* up = uS + (size_t)row * 1024 + d;
    float uv = b2f(up[0]) + b2f(up[512]);
    float xv = dtv * uv;
    float y = 0.f;
#pragma unroll
    for (int s = 0; s < 16; ++s) {
      h[s] = h[s] * __expf(dtv * A_r[s]) + xv * BC[t][s];
      y += h[s] * BC[t][16 + s];
    }
    float zv = xz[(size_t)row * 1024 + 512 + d];
    float sig = 1.f / (1.f + __expf(-zv));
    float v = (y + Dv * uv) * (zv * sig);
    u16 hh = f2b(v);
    u16 ll = f2b(v - b2f(hh));
    u16* rp = y2s + (size_t)row * 1024 + d;
    rp[0] = hh;
    rp[512] = ll;
  }
}

// ---------------- final head ----------------
__global__ __launch_bounds__(256) void k10_head(const float* __restrict__ pooled,
    const float* __restrict__ fc1_w, const float* __restrict__ fc1_b,
    const float* __restrict__ fc2_w, const float* __restrict__ fc2_b,
    float* __restrict__ out) {
  __shared__ float pl[1024];
  __shared__ float hbuf[4][128];
  int tid = threadIdx.x;
  for (int i = tid; i < 1024; i += 256) pl[i] = pooled[i];
  __syncthreads();
  for (int idx = tid; idx < 512; idx += 256) {
    int b = idx >> 7, i = idx & 127;
    float acc = fc1_b[i];
    for (int o = 0; o < 256; ++o) acc += pl[b * 256 + o] * fc1_w[i * 256 + o];
    hbuf[b][i] = fmaxf(acc, 0.f);
  }
  __syncthreads();
  if (tid < 16) {
    int b = tid >> 2, c = tid & 3;
    float acc = fc2_b[c];
    for (int i = 0; i < 128; ++i) acc += hbuf[b][i] * fc2_w[c * 128 + i];
    out[b * 4 + c] = acc;
  }
}

extern "C" void kernel_launch(void* const* d_in, const int* in_sizes, int n_in,
                              void* d_out, int out_size, void* d_ws, size_t ws_size,
                              hipStream_t stream) {
  (void)in_sizes; (void)n_in; (void)out_size; (void)ws_size;
  const float* x        = (const float*)d_in[0];
  const float* conv1_w  = (const float*)d_in[1];
  const float* conv1_b  = (const float*)d_in[2];
  const float* conv2_w  = (const float*)d_in[3];
  const float* conv2_b  = (const float*)d_in[4];
  const float* in_proj_w= (const float*)d_in[5];
  const float* dw_w     = (const float*)d_in[6];
  const float* dw_b     = (const float*)d_in[7];
  const float* x_proj_w = (const float*)d_in[8];
  const float* dt_proj_w= (const float*)d_in[9];
  const float* dt_proj_b= (const float*)d_in[10];
  const float* A_log    = (const float*)d_in[11];
  const float* D_param  = (const float*)d_in[12];
  const float* out_proj_w=(const float*)d_in[13];
  const float* fc1_w    = (const float*)d_in[14];
  const float* fc1_b    = (const float*)d_in[15];
  const float* fc2_w    = (const float*)d_in[16];
  const float* fc2_b    = (const float*)d_in[17];
  float* out = (float*)d_out;

  float* ws    = (float*)d_ws;
  float* f1A   = ws;                      // 3,145,728 f (8192x768 u16)
  float* fe    = f1A + 3145728;           // 2,097,152 f (8192x512 u16)
  float* wc2   = fe + 2097152;            //    49,152 f (256x384 u16)
  float* wi    = wc2 + 49152;             //   131,072 f (1024x256 u16)
  float* wo    = wi + 131072;             //    65,536 f (256x512 u16)
  float* wcb   = wo + 65536;              //   147,456 f (576x512 u16)
  float* xz    = wcb + 147456;            // 8,388,608 f
  float* uS    = xz + 8388608;            // 4,194,304 f (8192x1024 u16)
  float* xdbl  = uS + 4194304;            //   393,216 f
  float* dt    = xdbl + 393216;           // 4,194,304 f
  float* y2s   = dt + 4194304;            // 4,194,304 f (8192x1024 u16)
  float* pooled= y2s + 4194304;           //     1,024 f
  float* hloc  = pooled + 1024;           // 2,097,152 f
  float* h_in  = hloc + 2097152;          // 2,097,152 f
  float* dts   = h_in + 2097152;          //   131,072 f

  u16* f1Ap = (u16*)f1A;
  u16* fep  = (u16*)fe;
  u16* wc2p = (u16*)wc2;
  u16* wip  = (u16*)wi;
  u16* wop  = (u16*)wo;
  u16* wcbp = (u16*)wcb;
  u16* uSp  = (u16*)uS;
  u16* y2p  = (u16*)y2s;

  k1_conv1A<<<dim3(BB * LL * 128 / 256), dim3(256), 0, stream>>>(x, conv1_w, conv1_b, f1Ap);
  k_prep<<<dim3(3076), dim3(256), 0, stream>>>(conv2_w, in_proj_w, out_proj_w,
      x_proj_w, dt_proj_w, wc2p, wip, wop, wcbp, pooled);
  // conv2: (8192,768)=[H|L] x WH(256,384 wrapped), 32x64 tiles, EPI1
  k_mm<32, 64, 1, 4><<<dim3(4, 256), dim3(256), 0, stream>>>(f1Ap, wc2p, nullptr, conv2_b, fep, nullptr, 256, 768, 384);
  // in_proj: (8192,512)=[H|L] x WH(1024,256 wrapped), 64x64 tiles, EPI0
  k_mm<64, 64, 0, 16><<<dim3(16, 128), dim3(256), 0, stream>>>(fep, wip, xz, nullptr, nullptr, nullptr, 1024, 512, 256);
  k4_dwconv<<<dim3(BB * LL * 512 / 256), dim3(256), 0, stream>>>(xz, dw_w, dw_b, uSp);
  // dt + BC: (8192,1024)=[H|L] x WH(576,512 wrapped), 64x64 tiles, EPI3
  k_mm<64, 64, 3, 9><<<dim3(9, 128), dim3(256), 0, stream>>>(uSp, wcbp, dt, dt_proj_b, nullptr, xdbl, 576, 1024, 512);
  k7a_pass1<<<dim3(BB * NC), dim3(512), 0, stream>>>(dt, uSp, xdbl, A_log, hloc, dts);
  k7b_combine<<<dim3(BB * 16), dim3(512), 0, stream>>>(hloc, dts, A_log, h_in);
  k7c_pass3<<<dim3(BB * NC), dim3(512), 0, stream>>>(dt, uSp, xdbl, xz, A_log, D_param, h_in, y2p);
  // out_proj: (8192,1024)=[H|L] x WH(256,512 wrapped), 32x64 tiles, EPI2
  k_mm<32, 64, 2, 4><<<dim3(4, 256), dim3(256), 0, stream>>>(y2p, wop, pooled, nullptr, nullptr, nullptr, 256, 1024, 512);
  k10_head<<<dim3(1), dim3(256), 0, stream>>>(pooled, fc1_w, fc1_b, fc2_w, fc2_b, out);
}

// Round 16
// 207.257 us; speedup vs baseline: 1.0162x; 1.0162x over previous
//
#include <hip/hip_runtime.h>
#include <cfloat>

#define BB 4
#define LL 2048
#define DSTATE 16
#define CH 32
#define NC 64

typedef unsigned short u16;
typedef __attribute__((ext_vector_type(8))) short bf16x8;
typedef __attribute__((ext_vector_type(4))) float f32x4;

__device__ inline u16 f2b(float v) {
  union { float f; unsigned u; } c; c.f = v;
  unsigned r = c.u + 0x7fffu + ((c.u >> 16) & 1u);
  return (u16)(r >> 16);
}
__device__ inline float b2f(u16 h) {
  union { unsigned u; float f; } c; c.u = ((unsigned)h) << 16;
  return c.f;
}
__device__ inline void atomicMaxF(float* a, float v) {
  if (v >= 0.f) atomicMax((int*)a, __float_as_int(v));
  else atomicMin((unsigned int*)a, __float_as_uint(v));
}

#define GLOAD16(gsrc, ldst) \
  __builtin_amdgcn_global_load_lds( \
      (const __attribute__((address_space(1))) unsigned int*)(gsrc), \
      (__attribute__((address_space(3))) unsigned int*)(ldst), 16, 0, 0)

// ------- conv1 fused with im2col: x (B,L,9) -> A' (8192,768)=[Htaps|Ltaps] -------
__global__ __launch_bounds__(256) void k1_conv1A(const float* __restrict__ x,
    const float* __restrict__ w, const float* __restrict__ bias,
    u16* __restrict__ A) {
  int idx = blockIdx.x * 256 + threadIdx.x;  // (b,t,i)
  int i = idx & 127;
  int t = (idx >> 7) & (LL - 1);
  int b = idx >> 18;
  float acc = bias[i];
#pragma unroll
  for (int k = 0; k < 3; ++k) {
    int ts = t + k - 1;
    if (ts < 0 || ts >= LL) continue;
    const float* xr = x + (b * LL + ts) * 9;
    const float* wr = w + i * 27 + k;
#pragma unroll
    for (int c = 0; c < 9; ++c) acc += xr[c] * wr[c * 3];
  }
  float v = fmaxf(acc, 0.f);
  u16 h = f2b(v), l = f2b(v - b2f(h));
#pragma unroll
  for (int tap = 0; tap < 3; ++tap) {
    int rr = t + 1 - tap;
    if (rr < 0 || rr >= LL) continue;
    u16* rp = A + ((size_t)(b * LL + rr)) * 768 + tap * 128 + i;
    rp[0] = h; rp[384] = l;
  }
  if (t == 0) {
    u16* rp = A + ((size_t)(b * LL)) * 768 + i;
    rp[0] = 0; rp[384] = 0;
  }
  if (t == LL - 1) {
    u16* rp = A + ((size_t)(b * LL + LL - 1)) * 768 + 256 + i;
    rp[0] = 0; rp[384] = 0;
  }
}

// ------- ALL weight prep (bf16-H only) + combined dt/BC weight + pooled init ----
// ranges: [0,98304) conv2 WH taps (256,384); [98304,360448) in_proj WH (1024,256);
//         [360448,491520) out_proj WH (256,512); [491520,492544) pooled init;
//         [492544,787456) comb WH (576,512).
__global__ __launch_bounds__(256) void k_prep(const float* __restrict__ wc2,
    const float* __restrict__ wip, const float* __restrict__ wop,
    const float* __restrict__ xw, const float* __restrict__ dtw,
    u16* __restrict__ dc2, u16* __restrict__ dip, u16* __restrict__ dop,
    u16* __restrict__ dcb, float* __restrict__ pooled) {
  int idx = blockIdx.x * 256 + threadIdx.x;
  if (idx < 98304) {                        // conv2: (256,128,3) -> WH[o][tap*128+i]
    int o = idx / 384, r2 = idx - o * 384;
    int tap = r2 >> 7, i = r2 & 127;
    dc2[(size_t)o * 384 + r2] = f2b(wc2[o * 384 + i * 3 + tap]);
  } else if (idx < 360448) {                // in_proj (1024,256) -> WH
    int j = idx - 98304;
    dip[j] = f2b(wip[j]);
  } else if (idx < 491520) {                // out_proj (256,512) -> WH
    int j = idx - 360448;
    dop[j] = f2b(wop[j]);
  } else if (idx < 492544) {
    pooled[idx - 491520] = -FLT_MAX;
  } else if (idx < 787456) {                // comb: rows<512 dtw@xw16; 512..543 B/C; else 0
    int j = idx - 492544;                   // n*512 + k, n<576
    int n = j >> 9, k = j & 511;
    float v = 0.f;
    if (n < 512) {
      const float* dr = dtw + n * 16;
#pragma unroll
      for (int q = 0; q < 16; ++q) v += dr[q] * xw[q * 512 + k];
    } else if (n < 544) {
      v = xw[(16 + n - 512) * 512 + k];
    }
    dcb[(size_t)n * 512 + k] = f2b(v);
  }
}

// ======= m97-style MFMA GEMM: C = A[M,K] @ B'[N,K]^T, B stored width KB, wraps =======
// A = [H|L] activation split (exact), B = bf16 weights duplicated logically [WH|WH].
// EPI 0: fp32 C. EPI 1: bias+relu -> [H|L] (stride 512). EPI 2: max-pool atomic.
// EPI 3: cols<512 -> softplus(+bias) -> C; cols 512..543 -> xdb.
template <int TM, int TN, int EPI, int NBX>
__global__ __launch_bounds__(256) void k_mm(
    const u16* __restrict__ A, const u16* __restrict__ B,
    float* __restrict__ C, const float* __restrict__ bias,
    u16* __restrict__ osp, float* __restrict__ xdb, int N, int K, int KB) {
  constexpr int WM = TM / 2, WN = TN / 2;
  constexpr int NA = WM / 16, NB = WN / 16;
  __shared__ u16 As[2][TM * 64];
  __shared__ u16 Bs[2][TN * 64];
  __shared__ float cmw[2][TN];
  const int tid = threadIdx.x;
  const int lane = tid & 63;
  const int wid = tid >> 6;
  const int wr = wid >> 1, wc = wid & 1;
  int bid = blockIdx.y * NBX + blockIdx.x;
  int nwg = gridDim.y * NBX;
  int swz = (bid & 7) * (nwg >> 3) + (bid >> 3);
  int bm = swz / NBX;
  int bn = swz - bm * NBX;
  const int m0 = bm * TM, n0 = bn * TN;
  const int lrow = lane & 15, lg = lane >> 4;
  const int srow = tid >> 3, sg = tid & 7;
  const int NT = K >> 6;

  f32x4 acc[NA][NB] = {};

  auto stage = [&](int buf, int k0) {
#pragma unroll
    for (int r = 0; r < TM / 32; ++r) {
      int row = r * 32 + srow;
      const u16* src = A + (size_t)(m0 + row) * K + k0 + ((sg ^ (row & 7)) << 3);
      GLOAD16(src, &As[buf][row * 64 + (sg << 3)]);
    }
    int kb = (k0 < KB) ? k0 : k0 - KB;      // B wraps: logical [WH|WH]
#pragma unroll
    for (int r = 0; r < TN / 32; ++r) {
      int row = r * 32 + srow;
      const u16* src = B + (size_t)(n0 + row) * KB + kb + ((sg ^ (row & 7)) << 3);
      GLOAD16(src, &Bs[buf][row * 64 + (sg << 3)]);
    }
  };

  stage(0, 0);
  __syncthreads();
  for (int t = 0; t < NT; ++t) {
    int cur = t & 1;
    if (t + 1 < NT) stage(cur ^ 1, (t + 1) << 6);
#pragma unroll
    for (int kc = 0; kc < 2; ++kc) {
      bf16x8 af[NA], bfr[NB];
#pragma unroll
      for (int i = 0; i < NA; ++i) {
        int row = wr * WM + i * 16 + lrow;
        int g = (kc * 4 + lg) ^ (row & 7);
        af[i] = *(const bf16x8*)&As[cur][row * 64 + (g << 3)];
      }
#pragma unroll
      for (int j = 0; j < NB; ++j) {
        int row = wc * WN + j * 16 + lrow;
        int g = (kc * 4 + lg) ^ (row & 7);
        bfr[j] = *(const bf16x8*)&Bs[cur][row * 64 + (g << 3)];
      }
#pragma unroll
      for (int i = 0; i < NA; ++i)
#pragma unroll
        for (int j = 0; j < NB; ++j)
          acc[i][j] = __builtin_amdgcn_mfma_f32_16x16x32_bf16(af[i], bfr[j], acc[i][j], 0, 0, 0);
    }
    __syncthreads();
  }
  if constexpr (EPI == 2) {
    float mj[NB];
#pragma unroll
    for (int j = 0; j < NB; ++j) {
      float m = -FLT_MAX;
#pragma unroll
      for (int i = 0; i < NA; ++i)
#pragma unroll
        for (int r = 0; r < 4; ++r) m = fmaxf(m, acc[i][j][r]);
      m = fmaxf(m, __shfl_xor(m, 16, 64));
      m = fmaxf(m, __shfl_xor(m, 32, 64));
      mj[j] = m;
    }
    if (lane < 16) {
#pragma unroll
      for (int j = 0; j < NB; ++j)
        cmw[wr][wc * WN + j * 16 + lane] = mj[j];
    }
    __syncthreads();
    if (tid < TN) {
      float v = fmaxf(cmw[0][tid], cmw[1][tid]);
      atomicMaxF(&C[(m0 >> 11) * 256 + n0 + tid], v);
    }
  } else {
#pragma unroll
    for (int i = 0; i < NA; ++i)
#pragma unroll
      for (int j = 0; j < NB; ++j)
#pragma unroll
        for (int r = 0; r < 4; ++r) {
          int row = m0 + wr * WM + i * 16 + lg * 4 + r;
          int col = n0 + wc * WN + j * 16 + lrow;
          if constexpr (EPI == 0) {
            C[(size_t)row * N + col] = acc[i][j][r];
          } else if constexpr (EPI == 1) {
            float v = fmaxf(acc[i][j][r] + bias[col], 0.f);
            u16 h = f2b(v), l = f2b(v - b2f(h));
            u16* rp = osp + (size_t)row * 512;
            rp[col] = h;
            rp[256 + col] = l;
          } else {  // EPI == 3: dt softplus + BC scatter
            float v = acc[i][j][r];
            if (col < 512) {
              float a = v + bias[col];
              C[(size_t)row * 512 + col] = (a > 20.f) ? a : __logf(1.f + __expf(a));
            } else if (col < 544) {
              xdb[(size_t)row * 48 + 16 + (col - 512)] = v;
            }
          }
        }
  }
}

// ------- depthwise causal conv4 + silu: xz -> uS (8192,1024)=[H|L] -------
__global__ __launch_bounds__(256) void k4_dwconv(const float* __restrict__ xz,
    const float* __restrict__ w, const float* __restrict__ bias,
    u16* __restrict__ uS) {
  int idx = blockIdx.x * 256 + threadIdx.x;
  int d = idx & 511;
  int t = (idx >> 9) & (LL - 1);
  int b = idx >> 20;
  float acc = bias[d];
#pragma unroll
  for (int k = 0; k < 4; ++k) {
    int tt = t - 3 + k;
    if (tt >= 0) acc += xz[(b * LL + tt) * 1024 + d] * w[d * 4 + k];
  }
  float v = acc / (1.f + __expf(-acc));
  u16 h = f2b(v), l = f2b(v - b2f(h));
  u16* rp = uS + (size_t)(b * LL + t) * 1024 + d;
  rp[0] = h;
  rp[512] = l;
}

// ======== chunked selective scan: 3 passes (u = H+L from uS) ========
__global__ __launch_bounds__(512) void k7a_pass1(const float* __restrict__ dt,
    const u16* __restrict__ uS, const float* __restrict__ xdbl,
    const float* __restrict__ A_log, float* __restrict__ hloc,
    float* __restrict__ dtsum) {
  __shared__ float Bs[CH][16];
  int b = blockIdx.x >> 6;
  int c = blockIdx.x & (NC - 1);
  int d = threadIdx.x;
  {
    int t = threadIdx.x >> 4, s = threadIdx.x & 15;
    Bs[t][s] = xdbl[(b * LL + c * CH + t) * 48 + 16 + s];
  }
  __syncthreads();
  float A_r[16];
#pragma unroll
  for (int s = 0; s < 16; ++s) A_r[s] = -__expf(A_log[d * 16 + s]);
  float h[16];
#pragma unroll
  for (int s = 0; s < 16; ++s) h[s] = 0.f;
  float dsum = 0.f;
  const float* dtp = dt + (size_t)(b * LL + c * CH) * 512 + d;
  const u16* up = uS + (size_t)(b * LL + c * CH) * 1024 + d;
  for (int t = 0; t < CH; ++t) {
    float dtv = dtp[t * 512];
    float uv = b2f(up[t * 1024]) + b2f(up[t * 1024 + 512]);
    float xv = dtv * uv;
    dsum += dtv;
#pragma unroll
    for (int s = 0; s < 16; ++s)
      h[s] = h[s] * __expf(dtv * A_r[s]) + xv * Bs[t][s];
  }
  int base = b * NC + c;
#pragma unroll
  for (int s = 0; s < 16; ++s) hloc[(base * 16 + s) * 512 + d] = h[s];
  dtsum[base * 512 + d] = dsum;
}

__global__ __launch_bounds__(512) void k7b_combine(const float* __restrict__ hloc,
    const float* __restrict__ dtsum, const float* __restrict__ A_log,
    float* __restrict__ h_in) {
  int g = blockIdx.x * 512 + threadIdx.x;
  int d = g & 511;
  int s = (g >> 9) & 15;
  int b = g >> 13;
  float A_r = -__expf(A_log[d * 16 + s]);
  float H = 0.f;
  for (int c = 0; c < NC; ++c) {
    int base = b * NC + c;
    h_in[(base * 16 + s) * 512 + d] = H;
    float P = __expf(A_r * dtsum[base * 512 + d]);
    H = P * H + hloc[(base * 16 + s) * 512 + d];
  }
}

// pass3: replay + gate; writes y2s (8192,1024) = [H | L]
__global__ __launch_bounds__(512) void k7c_pass3(const float* __restrict__ dt,
    const u16* __restrict__ uS, const float* __restrict__ xdbl,
    const float* __restrict__ xz, const float* __restrict__ A_log,
    const float* __restrict__ D_param, const float* __restrict__ h_in,
    u16* __restrict__ y2s) {
  __shared__ float BC[CH][32];
  int b = blockIdx.x >> 6;
  int c = blockIdx.x & (NC - 1);
  int d = threadIdx.x;
  for (int i = threadIdx.x; i < CH * 32; i += 512) {
    int t = i >> 5, j = i & 31;
    BC[t][j] = xdbl[(b * LL + c * CH + t) * 48 + 16 + j];
  }
  __syncthreads();
  float A_r[16];
#pragma unroll
  for (int s = 0; s < 16; ++s) A_r[s] = -__expf(A_log[d * 16 + s]);
  float Dv = D_param[d];
  int base = b * NC + c;
  float h[16];
#pragma unroll
  for (int s = 0; s < 16; ++s) h[s] = h_in[(base * 16 + s) * 512 + d];
  for (int t = 0; t < CH; ++t) {
    int row = b * LL + c * CH + t;
    float dtv = dt[(size_t)row * 512 + d];
    const u16* up = uS + (size_t)row * 1024 + d;
    float uv = b2f(up[0]) + b2f(up[512]);
    float xv = dtv * uv;
    float y = 0.f;
#pragma unroll
    for (int s = 0; s < 16; ++s) {
      h[s] = h[s] * __expf(dtv * A_r[s]) + xv * BC[t][s];
      y += h[s] * BC[t][16 + s];
    }
    float zv = xz[(size_t)row * 1024 + 512 + d];
    float sig = 1.f / (1.f + __expf(-zv));
    float v = (y + Dv * uv) * (zv * sig);
    u16 hh = f2b(v);
    u16 ll = f2b(v - b2f(hh));
    u16* rp = y2s + (size_t)row * 1024 + d;
    rp[0] = hh;
    rp[512] = ll;
  }
}

// ---------------- final head ----------------
__global__ __launch_bounds__(256) void k10_head(const float* __restrict__ pooled,
    const float* __restrict__ fc1_w, const float* __restrict__ fc1_b,
    const float* __restrict__ fc2_w, const float* __restrict__ fc2_b,
    float* __restrict__ out) {
  __shared__ float pl[1024];
  __shared__ float hbuf[4][128];
  int tid = threadIdx.x;
  for (int i = tid; i < 1024; i += 256) pl[i] = pooled[i];
  __syncthreads();
  for (int idx = tid; idx < 512; idx += 256) {
    int b = idx >> 7, i = idx & 127;
    float acc = fc1_b[i];
    for (int o = 0; o < 256; ++o) acc += pl[b * 256 + o] * fc1_w[i * 256 + o];
    hbuf[b][i] = fmaxf(acc, 0.f);
  }
  __syncthreads();
  if (tid < 16) {
    int b = tid >> 2, c = tid & 3;
    float acc = fc2_b[c];
    for (int i = 0; i < 128; ++i) acc += hbuf[b][i] * fc2_w[c * 128 + i];
    out[b * 4 + c] = acc;
  }
}

extern "C" void kernel_launch(void* const* d_in, const int* in_sizes, int n_in,
                              void* d_out, int out_size, void* d_ws, size_t ws_size,
                              hipStream_t stream) {
  (void)in_sizes; (void)n_in; (void)out_size; (void)ws_size;
  const float* x        = (const float*)d_in[0];
  const float* conv1_w  = (const float*)d_in[1];
  const float* conv1_b  = (const float*)d_in[2];
  const float* conv2_w  = (const float*)d_in[3];
  const float* conv2_b  = (const float*)d_in[4];
  const float* in_proj_w= (const float*)d_in[5];
  const float* dw_w     = (const float*)d_in[6];
  const float* dw_b     = (const float*)d_in[7];
  const float* x_proj_w = (const float*)d_in[8];
  const float* dt_proj_w= (const float*)d_in[9];
  const float* dt_proj_b= (const float*)d_in[10];
  const float* A_log    = (const float*)d_in[11];
  const float* D_param  = (const float*)d_in[12];
  const float* out_proj_w=(const float*)d_in[13];
  const float* fc1_w    = (const float*)d_in[14];
  const float* fc1_b    = (const float*)d_in[15];
  const float* fc2_w    = (const float*)d_in[16];
  const float* fc2_b    = (const float*)d_in[17];
  float* out = (float*)d_out;

  float* ws    = (float*)d_ws;
  float* f1A   = ws;                      // 3,145,728 f (8192x768 u16)
  float* fe    = f1A + 3145728;           // 2,097,152 f (8192x512 u16)
  float* wc2   = fe + 2097152;            //    49,152 f (256x384 u16)
  float* wi    = wc2 + 49152;             //   131,072 f (1024x256 u16)
  float* wo    = wi + 131072;             //    65,536 f (256x512 u16)
  float* wcb   = wo + 65536;              //   147,456 f (576x512 u16)
  float* xz    = wcb + 147456;            // 8,388,608 f
  float* uS    = xz + 8388608;            // 4,194,304 f (8192x1024 u16)
  float* xdbl  = uS + 4194304;            //   393,216 f
  float* dt    = xdbl + 393216;           // 4,194,304 f
  float* y2s   = dt + 4194304;            // 4,194,304 f (8192x1024 u16)
  float* pooled= y2s + 4194304;           //     1,024 f
  float* hloc  = pooled + 1024;           // 2,097,152 f
  float* h_in  = hloc + 2097152;          // 2,097,152 f
  float* dts   = h_in + 2097152;          //   131,072 f

  u16* f1Ap = (u16*)f1A;
  u16* fep  = (u16*)fe;
  u16* wc2p = (u16*)wc2;
  u16* wip  = (u16*)wi;
  u16* wop  = (u16*)wo;
  u16* wcbp = (u16*)wcb;
  u16* uSp  = (u16*)uS;
  u16* y2p  = (u16*)y2s;

  k1_conv1A<<<dim3(BB * LL * 128 / 256), dim3(256), 0, stream>>>(x, conv1_w, conv1_b, f1Ap);
  k_prep<<<dim3(3076), dim3(256), 0, stream>>>(conv2_w, in_proj_w, out_proj_w,
      x_proj_w, dt_proj_w, wc2p, wip, wop, wcbp, pooled);
  // conv2: (8192,768)=[H|L] x WH(256,384 wrapped), 32x64 tiles, EPI1
  k_mm<32, 64, 1, 4><<<dim3(4, 256), dim3(256), 0, stream>>>(f1Ap, wc2p, nullptr, conv2_b, fep, nullptr, 256, 768, 384);
  // in_proj: (8192,512)=[H|L] x WH(1024,256 wrapped), 64x64 tiles, EPI0
  k_mm<64, 64, 0, 16><<<dim3(16, 128), dim3(256), 0, stream>>>(fep, wip, xz, nullptr, nullptr, nullptr, 1024, 512, 256);
  k4_dwconv<<<dim3(BB * LL * 512 / 256), dim3(256), 0, stream>>>(xz, dw_w, dw_b, uSp);
  // dt + BC: (8192,1024)=[H|L] x WH(576,512 wrapped), 64x64 tiles, EPI3
  k_mm<64, 64, 3, 9><<<dim3(9, 128), dim3(256), 0, stream>>>(uSp, wcbp, dt, dt_proj_b, nullptr, xdbl, 576, 1024, 512);
  k7a_pass1<<<dim3(BB * NC), dim3(512), 0, stream>>>(dt, uSp, xdbl, A_log, hloc, dts);
  k7b_combine<<<dim3(BB * 16), dim3(512), 0, stream>>>(hloc, dts, A_log, h_in);
  k7c_pass3<<<dim3(BB * NC), dim3(512), 0, stream>>>(dt, uSp, xdbl, xz, A_log, D_param, h_in, y2p);
  // out_proj: (8192,1024)=[H|L] x WH(256,512 wrapped), 32x64 tiles, EPI2
  k_mm<32, 64, 2, 4><<<dim3(4, 256), dim3(256), 0, stream>>>(y2p, wop, pooled, nullptr, nullptr, nullptr, 256, 1024, 512);
  k10_head<<<dim3(1), dim3(256), 0, stream>>>(pooled, fc1_w, fc1_b, fc2_w, fc2_b, out);
}